// Round 13
// baseline (10719.312 us; speedup 1.0000x reference)
//
#include <hip/hip_runtime.h>

// LSTM T=4096, I=512, H=2048, 4H=8192, O=1, fp32.
// R13 = R12 (4-replica mailbox, tail on wave 0, wave-1 backoff, fast_tanh)
//  + cross-step poll prefetch: round-0 loads for step s+1 issued right after
//    the part[] write, overlapping B2+tail with the load RTT
//  + s_setprio 3 on wave 0 so the tail wins CU issue arbitration.
// h published as tagged u64 (fp32bits<<32 | step), parity double buffer.

#define T_STEPS 4096
#define HID     2048
#define GATES   8192
#define KIN     512
#define NWG     256
#define NTHR    512
#define NREP    4
#define XG_BYTES ((size_t)T_STEPS * GATES * 4)
#define HCOM_BYTES ((size_t)NREP * 2 * HID * 8)   // 128 KB

typedef float v2f __attribute__((ext_vector_type(2)));

__device__ __forceinline__ float u2f(unsigned int u) {
    union { unsigned int u; float f; } x; x.u = u; return x.f;
}
__device__ __forceinline__ float fast_sigmoid(float x) {
    return 1.f / (1.f + __expf(-x));
}
__device__ __forceinline__ float fast_tanh(float x) {
    return 2.f / (1.f + __expf(-2.f * x)) - 1.f;
}

// ---------------- xg = X @ Wih^T + (bih+bhh), fp32 tiled ----------------
__global__ __launch_bounds__(256) void gemm_xg(const float* __restrict__ A,
                                               const float* __restrict__ B,
                                               const float* __restrict__ bih,
                                               const float* __restrict__ bhh,
                                               float* __restrict__ C) {
    __shared__ float As[32][68];
    __shared__ float Bs[32][68];
    const int t  = threadIdx.x;
    const int tx = t & 15, ty = t >> 4;
    const int m0 = blockIdx.y * 64, n0 = blockIdx.x * 64;
    const int sr = t >> 3, sc = (t & 7) * 4;

    float c[4][4] = {};
    for (int k0 = 0; k0 < KIN; k0 += 32) {
        float4 a0 = *(const float4*)(A + (size_t)(m0 + sr)      * KIN + k0 + sc);
        float4 a1 = *(const float4*)(A + (size_t)(m0 + sr + 32) * KIN + k0 + sc);
        float4 b0 = *(const float4*)(B + (size_t)(n0 + sr)      * KIN + k0 + sc);
        float4 b1 = *(const float4*)(B + (size_t)(n0 + sr + 32) * KIN + k0 + sc);
        __syncthreads();
        As[sc+0][sr] = a0.x; As[sc+1][sr] = a0.y; As[sc+2][sr] = a0.z; As[sc+3][sr] = a0.w;
        As[sc+0][sr+32] = a1.x; As[sc+1][sr+32] = a1.y; As[sc+2][sr+32] = a1.z; As[sc+3][sr+32] = a1.w;
        Bs[sc+0][sr] = b0.x; Bs[sc+1][sr] = b0.y; Bs[sc+2][sr] = b0.z; Bs[sc+3][sr] = b0.w;
        Bs[sc+0][sr+32] = b1.x; Bs[sc+1][sr+32] = b1.y; Bs[sc+2][sr+32] = b1.z; Bs[sc+3][sr+32] = b1.w;
        __syncthreads();
#pragma unroll
        for (int kk = 0; kk < 32; ++kk) {
            float4 av = *(const float4*)&As[kk][ty * 4];
            float4 bv = *(const float4*)&Bs[kk][tx * 4];
            c[0][0] = fmaf(av.x, bv.x, c[0][0]); c[0][1] = fmaf(av.x, bv.y, c[0][1]);
            c[0][2] = fmaf(av.x, bv.z, c[0][2]); c[0][3] = fmaf(av.x, bv.w, c[0][3]);
            c[1][0] = fmaf(av.y, bv.x, c[1][0]); c[1][1] = fmaf(av.y, bv.y, c[1][1]);
            c[1][2] = fmaf(av.y, bv.z, c[1][2]); c[1][3] = fmaf(av.y, bv.w, c[1][3]);
            c[2][0] = fmaf(av.z, bv.x, c[2][0]); c[2][1] = fmaf(av.z, bv.y, c[2][1]);
            c[2][2] = fmaf(av.z, bv.z, c[2][2]); c[2][3] = fmaf(av.z, bv.w, c[2][3]);
            c[3][0] = fmaf(av.w, bv.x, c[3][0]); c[3][1] = fmaf(av.w, bv.y, c[3][1]);
            c[3][2] = fmaf(av.w, bv.z, c[3][2]); c[3][3] = fmaf(av.w, bv.w, c[3][3]);
        }
    }
    const int col = n0 + tx * 4;
    float4 bias;
    bias.x = bih[col]   + bhh[col];
    bias.y = bih[col+1] + bhh[col+1];
    bias.z = bih[col+2] + bhh[col+2];
    bias.w = bih[col+3] + bhh[col+3];
#pragma unroll
    for (int i = 0; i < 4; ++i) {
        float4 o;
        o.x = c[i][0] + bias.x; o.y = c[i][1] + bias.y;
        o.z = c[i][2] + bias.z; o.w = c[i][3] + bias.w;
        *(float4*)(C + (size_t)(m0 + ty * 4 + i) * GATES + col) = o;
    }
}

// ---------------- persistent recurrence ----------------
// 256 WGs x 512 thr. WG owns hidden [8b,8b+8) = 32 gate rows.
// kc=t&127 (k subset {g*128+kc}), rg=t>>7 gate group, 8 rows each.
// Waves 0-1 poll replica (wg&3) + rebroadcast via LDS; tail on wave 0.
// hcom layout: replica r, parity p at hcom + (r*2+p)*HID.
template<int USE_XG>
__global__ __launch_bounds__(NTHR, 2) void lstm_rec(
    const float* __restrict__ X,
    const float* __restrict__ Wih,
    const float* __restrict__ xg,
    const float* __restrict__ Whh,
    const float* __restrict__ bih,
    const float* __restrict__ bhh,
    unsigned long long* __restrict__ hcom)
{
    const int t  = threadIdx.x;
    const int kc = t & 127;
    const int rg = t >> 7;
    const int j0 = blockIdx.x * 8;
    const int rep = blockIdx.x & (NREP - 1);

    // tail wave (wave 0) wins CU issue arbitration: earlier publish
    if (t < 64) asm volatile("s_setprio 3");

    // register-resident W_hh slice, packed as float2 pairs over g
    v2f whh2[8][8];
#pragma unroll
    for (int m = 0; m < 8; ++m) {
        const float* wr = Whh + (size_t)(rg * HID + j0 + m) * HID + kc;
#pragma unroll
        for (int j = 0; j < 8; ++j) {
            v2f p; p.x = wr[(2 * j) * 128]; p.y = wr[(2 * j + 1) * 128];
            whh2[m][j] = p;
        }
    }
    float wih[8][4];
    if (!USE_XG) {
#pragma unroll
        for (int m = 0; m < 8; ++m) {
            float4 vx = *(const float4*)(Wih + (size_t)(rg * HID + j0 + m) * KIN + kc * 4);
            wih[m][0] = vx.x; wih[m][1] = vx.y; wih[m][2] = vx.z; wih[m][3] = vx.w;
        }
    }

    float brow = 0.f;
    if (t < 32) {
        const int grow = (t >> 3) * HID + j0 + (t & 7);
        brow = bih[grow] + bhh[grow];
    }

    __shared__ float hshare[HID];
    __shared__ float part[32 * 132];
    float c_state = 0.f;

    // prime: round-0 prefetch for step 0 (parity 0)
    unsigned long long v[16];
    if (t < 128) {
        const unsigned long long* hp0 = hcom + ((size_t)rep * 2 + 0) * HID;
#pragma unroll
        for (int g = 0; g < 16; ++g)
            v[g] = __hip_atomic_load(hp0 + g * 128 + kc, __ATOMIC_RELAXED,
                                     __HIP_MEMORY_SCOPE_AGENT);
    }

    for (int s = 0; s < T_STEPS; ++s) {
        // prefetch xg (reducer rows) early — hides HBM/LLC latency
        float xgv = 0.f;
        if (USE_XG && t < 32)
            xgv = xg[(size_t)s * GATES + (t >> 3) * HID + j0 + (t & 7)];

        v2f hv2[8];
        if (t < 128) {
            // v[] holds the prefetched round-0 values for step s.
            const unsigned long long* hp = hcom + ((size_t)rep * 2 + (s & 1)) * HID;
            int guard = 1 << 18;
            int first = 1;
            for (;;) {
                bool ok = true;
#pragma unroll
                for (int g = 0; g < 16; ++g)
                    ok &= ((unsigned int)v[g] >= (unsigned int)s);
                if (ok || --guard <= 0) break;
                // backoff before the first RETRY: wave 1 avoids storming the
                // publish window (R11 lesson); subsequent rounds pace gently.
                if (first && t >= 64) __builtin_amdgcn_s_sleep(8);
                else __builtin_amdgcn_s_sleep(1);
                first = 0;
#pragma unroll
                for (int g = 0; g < 16; ++g)
                    v[g] = __hip_atomic_load(hp + g * 128 + kc, __ATOMIC_RELAXED,
                                             __HIP_MEMORY_SCOPE_AGENT);
            }
#pragma unroll
            for (int j = 0; j < 8; ++j) {
                v2f p;
                p.x = u2f((unsigned int)(v[2 * j] >> 32));
                p.y = u2f((unsigned int)(v[2 * j + 1] >> 32));
                hv2[j] = p;
                hshare[(2 * j) * 128 + kc]     = p.x;
                hshare[(2 * j + 1) * 128 + kc] = p.y;
            }
        }
        __syncthreads();                     // B1: hshare ready
        if (t >= 128) {
#pragma unroll
            for (int j = 0; j < 8; ++j) {
                v2f p;
                p.x = hshare[(2 * j) * 128 + kc];
                p.y = hshare[(2 * j + 1) * 128 + kc];
                hv2[j] = p;
            }
        }

        v2f acc2[8];
        if (!USE_XG) {
            float4 x4 = *(const float4*)(X + (size_t)s * KIN + kc * 4);
#pragma unroll
            for (int m = 0; m < 8; ++m) {
                float a = wih[m][0] * x4.x;
                a = fmaf(wih[m][1], x4.y, a);
                a = fmaf(wih[m][2], x4.z, a);
                a = fmaf(wih[m][3], x4.w, a);
                v2f z; z.x = a; z.y = 0.f; acc2[m] = z;
            }
        } else {
#pragma unroll
            for (int m = 0; m < 8; ++m) { v2f z; z.x = 0.f; z.y = 0.f; acc2[m] = z; }
        }

        // packed dot: 64 v_pk_fma_f32 per thread
#pragma unroll
        for (int m = 0; m < 8; ++m) {
            v2f a = acc2[m];
#pragma unroll
            for (int j = 0; j < 8; ++j)
                a = __builtin_elementwise_fma(whh2[m][j], hv2[j], a);
            acc2[m] = a;
        }
#pragma unroll
        for (int m = 0; m < 8; ++m)
            part[(rg * 8 + m) * 132 + kc] = acc2[m].x + acc2[m].y;

        // cross-step prefetch: issue round-0 loads for step s+1 NOW, so the
        // RTT overlaps B2 + tail. Safe: tags are monotone — stale tags (<s+1)
        // simply fail the check and get re-loaded.
        if (t < 128) {
            const unsigned long long* hpn =
                hcom + ((size_t)rep * 2 + ((s + 1) & 1)) * HID;
#pragma unroll
            for (int g = 0; g < 16; ++g)
                v[g] = __hip_atomic_load(hpn + g * 128 + kc, __ATOMIC_RELAXED,
                                         __HIP_MEMORY_SCOPE_AGENT);
        }
        __syncthreads();                     // B2: partials ready

        // tail: 64 threads reduce (2 per row), shuffle combine, 8 threads gate
        if (t < 64) {
            const int row = t & 31, half = t >> 5;
            const float4* p4 = (const float4*)(part + row * 132 + half * 64);
            float s0 = 0.f, s1 = 0.f, s2 = 0.f, s3 = 0.f;
#pragma unroll
            for (int i = 0; i < 16; ++i) {
                float4 pv = p4[i];
                s0 += pv.x; s1 += pv.y; s2 += pv.z; s3 += pv.w;
            }
            float sum = (s0 + s1) + (s2 + s3);
            sum += __shfl_xor(sum, 32, 64);  // combine the two halves
            sum += brow + xgv;               // valid on t<32 (rows)
            const float a1 = __shfl_down(sum, 8, 64);
            const float a2 = __shfl_down(sum, 16, 64);
            const float a3 = __shfl_down(sum, 24, 64);
            if (t < 8) {
                const float i_s = fast_sigmoid(sum);   // gate i (row t)
                const float f_s = fast_sigmoid(a1);    // gate f (row 8+t)
                const float g_t = fast_tanh(a2);       // gate g (row 16+t)
                const float o_s = fast_sigmoid(a3);    // gate o (row 24+t)
                c_state = f_s * c_state + i_s * g_t;
                const float h = o_s * fast_tanh(c_state);
                const unsigned long long pk =
                    ((unsigned long long)__float_as_uint(h) << 32) | (unsigned int)(s + 1);
                const size_t slot = (size_t)((s + 1) & 1) * HID + j0 + t;
#pragma unroll
                for (int r = 0; r < NREP; ++r)
                    __hip_atomic_store(&hcom[(size_t)r * 2 * HID + slot], pk,
                                       __ATOMIC_RELAXED, __HIP_MEMORY_SCOPE_AGENT);
            }
        }
        // reuse safety (per replica): overwriting parity-p slot s with s+2
        // requires THIS WG to pass poll(s+1), which requires every WG
        // (incl. any reader still at step s) to have published s+1 — which
        // they only do after finishing step s. Same invariant as R11/R12.
    }
}

// ---------------- out[0] = h_T . W_lin + b_lin ----------------
__global__ __launch_bounds__(256) void final_linear(const unsigned long long* __restrict__ hcom,
                                                    const float* __restrict__ Wlin,
                                                    const float* __restrict__ blin,
                                                    float* __restrict__ out) {
    __shared__ float red[4];
    const int t = threadIdx.x;
    float a = 0.f;
#pragma unroll
    for (int e = 0; e < 8; ++e) {
        const int idx = t * 8 + e;   // replica 0, parity 0 holds h_T (tag 4096)
        a = fmaf(Wlin[idx], u2f((unsigned int)(hcom[idx] >> 32)), a);
    }
#pragma unroll
    for (int m = 1; m < 64; m <<= 1) a += __shfl_xor(a, m, 64);
    if ((t & 63) == 0) red[t >> 6] = a;
    __syncthreads();
    if (t == 0) out[0] = red[0] + red[1] + red[2] + red[3] + blin[0];
}

extern "C" void kernel_launch(void* const* d_in, const int* in_sizes, int n_in,
                              void* d_out, int out_size, void* d_ws, size_t ws_size,
                              hipStream_t stream) {
    const float* X    = (const float*)d_in[0];
    const float* Wih  = (const float*)d_in[1];
    const float* Whh  = (const float*)d_in[2];
    const float* bih  = (const float*)d_in[3];
    const float* bhh  = (const float*)d_in[4];
    const float* Wlin = (const float*)d_in[5];
    const float* blin = (const float*)d_in[6];
    float* out = (float*)d_out;

    char* ws = (char*)d_ws;
    const bool big = ws_size >= XG_BYTES + HCOM_BYTES;

    if (big) {
        float* xg = (float*)ws;
        unsigned long long* hcom = (unsigned long long*)(ws + XG_BYTES);
        (void)hipMemsetAsync(hcom, 0, HCOM_BYTES, stream);
        gemm_xg<<<dim3(GATES / 64, T_STEPS / 64), 256, 0, stream>>>(X, Wih, bih, bhh, xg);
        lstm_rec<1><<<dim3(NWG), dim3(NTHR), 0, stream>>>(X, Wih, xg, Whh, bih, bhh, hcom);
        final_linear<<<1, 256, 0, stream>>>(hcom, Wlin, blin, out);
    } else {
        unsigned long long* hcom = (unsigned long long*)ws;
        (void)hipMemsetAsync(hcom, 0, HCOM_BYTES, stream);
        lstm_rec<0><<<dim3(NWG), dim3(NTHR), 0, stream>>>(X, Wih, nullptr, Whh, bih, bhh, hcom);
        final_linear<<<1, 256, 0, stream>>>(hcom, Wlin, blin, out);
    }
}